// Round 2
// baseline (234.779 us; speedup 1.0000x reference)
//
#include <hip/hip_runtime.h>
#include <hip/hip_cooperative_groups.h>

namespace cg = cooperative_groups;

// PlayCell hysteresis scan:
//   y[t]   = kernel * x[t]
//   out[t] = min(max(out[t-1], y[t]), y[t] + W)   (play operator, W = 1.0)
// Clamp maps are closed under composition -> associative scan over (L,H).
// combine(a then b): L = min(max(La,Lb),Hb), H = min(max(Ha,Lb),Hb).

#define T_LEN   16777216
#define NTH     256
#define SEG     64
#define NB      (T_LEN / (NTH * SEG))   // 1024 blocks: NB*NTH*SEG == T_LEN
#define WPLAY   1.0f

__device__ __forceinline__ void combine(float La, float Ha, float Lb, float Hb,
                                        float& Lo, float& Ho) {
    Lo = fminf(fmaxf(La, Lb), Hb);
    Ho = fminf(fmaxf(Ha, Lb), Hb);
}

__device__ __forceinline__ unsigned long long packLH(float L, float H) {
    return ((unsigned long long)__float_as_uint(H) << 32) | (unsigned long long)__float_as_uint(L);
}
__device__ __forceinline__ void unpackLH(unsigned long long u, float& L, float& H) {
    L = __uint_as_float((unsigned)(u & 0xffffffffull));
    H = __uint_as_float((unsigned)(u >> 32));
}

// =============== fused cooperative single-pass kernel ===============
__global__ __launch_bounds__(NTH, 4) void fused(const float* __restrict__ x,
                                                const float* __restrict__ kptr,
                                                const float* __restrict__ s0ptr,
                                                unsigned long long* __restrict__ bsum,
                                                float* __restrict__ out) {
    const float k  = kptr[0];
    const int tid  = threadIdx.x;
    const int bid  = blockIdx.x;
    const int lane = tid & 63;
    const int wid  = tid >> 6;
    const long base = ((long)bid * NTH + tid) * SEG;
    const float4* xv = (const float4*)(x + base);

    // ---- load this thread's 64 elements into registers (read x ONCE) ----
    float4 vs[SEG / 4];
#pragma unroll
    for (int i = 0; i < SEG / 4; ++i) vs[i] = xv[i];

    // ---- phase 1: thread clamp summary ----
    float L = -INFINITY, H = INFINITY;
#pragma unroll
    for (int i = 0; i < SEG / 4; ++i) {
        float y;
        y = k * vs[i].x; L = fminf(fmaxf(L, y), y + WPLAY); H = fminf(fmaxf(H, y), y + WPLAY);
        y = k * vs[i].y; L = fminf(fmaxf(L, y), y + WPLAY); H = fminf(fmaxf(H, y), y + WPLAY);
        y = k * vs[i].z; L = fminf(fmaxf(L, y), y + WPLAY); H = fminf(fmaxf(H, y), y + WPLAY);
        y = k * vs[i].w; L = fminf(fmaxf(L, y), y + WPLAY); H = fminf(fmaxf(H, y), y + WPLAY);
    }

    // ordered wave inclusive scan
#pragma unroll
    for (int d = 1; d < 64; d <<= 1) {
        float Lp = __shfl_up(L, d);
        float Hp = __shfl_up(H, d);
        if (lane >= d) { float Ln, Hn; combine(Lp, Hp, L, H, Ln, Hn); L = Ln; H = Hn; }
    }
    // wave-exclusive prefix
    float eL = __shfl_up(L, 1), eH = __shfl_up(H, 1);
    if (lane == 0) { eL = -INFINITY; eH = INFINITY; }

    __shared__ float wL[NTH / 64], wH[NTH / 64];
    if (lane == 63) { wL[wid] = L; wH[wid] = H; }
    __syncthreads();

    // block summary -> publish via device-scope 8B atomic (cross-XCD safe,
    // no false sharing on the summary array)
    if (tid == 0) {
        float Lt = wL[0], Ht = wH[0];
#pragma unroll
        for (int w = 1; w < NTH / 64; ++w) {
            float Ln, Hn; combine(Lt, Ht, wL[w], wH[w], Ln, Hn); Lt = Ln; Ht = Hn;
        }
        __hip_atomic_store(&bsum[bid], packLH(Lt, Ht),
                           __ATOMIC_RELAXED, __HIP_MEMORY_SCOPE_AGENT);
    }

    // thread-exclusive prefix WITHIN block (pair form; applied after sync)
    float peL = -INFINITY, peH = INFINITY;
    for (int w = 0; w < wid; ++w) {
        float Ln, Hn; combine(peL, peH, wL[w], wH[w], Ln, Hn); peL = Ln; peH = Hn;
    }
    { float Ln, Hn; combine(peL, peH, eL, eH, Ln, Hn); peL = Ln; peH = Hn; }

    // ---- grid-wide sync: all block summaries published ----
    cg::this_grid().sync();

    // ---- phase 2: every block redundantly scans the NB summaries ----
    const int Q = NB / NTH;  // 4
    float SL[Q], SH[Q];
    float TL = -INFINITY, TH = INFINITY;
#pragma unroll
    for (int j = 0; j < Q; ++j) {
        unsigned long long u = __hip_atomic_load(&bsum[tid * Q + j],
                                                 __ATOMIC_RELAXED, __HIP_MEMORY_SCOPE_AGENT);
        unpackLH(u, SL[j], SH[j]);
        float Ln, Hn; combine(TL, TH, SL[j], SH[j], Ln, Hn); TL = Ln; TH = Hn;
    }
#pragma unroll
    for (int d = 1; d < 64; d <<= 1) {
        float Lp = __shfl_up(TL, d);
        float Hp = __shfl_up(TH, d);
        if (lane >= d) { float Ln, Hn; combine(Lp, Hp, TL, TH, Ln, Hn); TL = Ln; TH = Hn; }
    }
    float xeL = __shfl_up(TL, 1), xeH = __shfl_up(TH, 1);
    if (lane == 0) { xeL = -INFINITY; xeH = INFINITY; }

    __shared__ float vL[NTH / 64], vH[NTH / 64];
    __shared__ float ebL, ebH;
    if (lane == 63) { vL[wid] = TL; vH[wid] = TH; }
    __syncthreads();

    // the one thread owning index `bid` computes this block's entering clamp
    {
        const int owner = bid / Q, off = bid % Q;
        if (tid == owner) {
            float aL = -INFINITY, aH = INFINITY;
            for (int w = 0; w < wid; ++w) {
                float Ln, Hn; combine(aL, aH, vL[w], vH[w], Ln, Hn); aL = Ln; aH = Hn;
            }
            { float Ln, Hn; combine(aL, aH, xeL, xeH, Ln, Hn); aL = Ln; aH = Hn; }
            for (int j = 0; j < off; ++j) {
                float Ln, Hn; combine(aL, aH, SL[j], SH[j], Ln, Hn); aL = Ln; aH = Hn;
            }
            ebL = aL; ebH = aH;
        }
    }
    __syncthreads();

    // ---- phase 3: entering state for this thread, serial emit from regs ----
    float s = fminf(fmaxf(s0ptr[0], ebL), ebH);  // block entering state
    s = fminf(fmaxf(s, peL), peH);               // + in-block thread prefix

    float4* ov = (float4*)(out + base);
#pragma unroll
    for (int i = 0; i < SEG / 4; ++i) {
        float4 o; float y;
        y = k * vs[i].x; s = fminf(fmaxf(s, y), y + WPLAY); o.x = s;
        y = k * vs[i].y; s = fminf(fmaxf(s, y), y + WPLAY); o.y = s;
        y = k * vs[i].z; s = fminf(fmaxf(s, y), y + WPLAY); o.z = s;
        y = k * vs[i].w; s = fminf(fmaxf(s, y), y + WPLAY); o.w = s;
        ov[i] = o;
    }
}

// =============== fallback: proven 3-pass path (round-1 kernel) ===============
#define FNB 2048
#define FSEG 32

__global__ __launch_bounds__(NTH) void pass1(const float* __restrict__ x,
                                             const float* __restrict__ kptr,
                                             float* __restrict__ bsum) {
    const float k  = kptr[0];
    const int tid  = threadIdx.x;
    const int bid  = blockIdx.x;
    const int lane = tid & 63;
    const int wid  = tid >> 6;
    const long base = ((long)bid * NTH + tid) * FSEG;
    const float4* xv = (const float4*)(x + base);

    float L = -INFINITY, H = INFINITY;
#pragma unroll
    for (int i = 0; i < FSEG / 4; ++i) {
        float4 v = xv[i]; float y;
        y = k * v.x; L = fminf(fmaxf(L, y), y + WPLAY); H = fminf(fmaxf(H, y), y + WPLAY);
        y = k * v.y; L = fminf(fmaxf(L, y), y + WPLAY); H = fminf(fmaxf(H, y), y + WPLAY);
        y = k * v.z; L = fminf(fmaxf(L, y), y + WPLAY); H = fminf(fmaxf(H, y), y + WPLAY);
        y = k * v.w; L = fminf(fmaxf(L, y), y + WPLAY); H = fminf(fmaxf(H, y), y + WPLAY);
    }
#pragma unroll
    for (int d = 1; d < 64; d <<= 1) {
        float Lp = __shfl_xor(L, d), Hp = __shfl_xor(H, d);
        float Ln, Hn;
        if (lane & d) combine(Lp, Hp, L, H, Ln, Hn);
        else          combine(L, H, Lp, Hp, Ln, Hn);
        L = Ln; H = Hn;
    }
    __shared__ float wL[NTH / 64], wH[NTH / 64];
    if (lane == 0) { wL[wid] = L; wH[wid] = H; }
    __syncthreads();
    if (tid == 0) {
        float Lt = wL[0], Ht = wH[0];
#pragma unroll
        for (int w = 1; w < NTH / 64; ++w) {
            float Ln, Hn; combine(Lt, Ht, wL[w], wH[w], Ln, Hn); Lt = Ln; Ht = Hn;
        }
        bsum[2 * bid] = Lt; bsum[2 * bid + 1] = Ht;
    }
}

__global__ __launch_bounds__(NTH) void pass2(const float* __restrict__ bsum,
                                             const float* __restrict__ s0ptr,
                                             float* __restrict__ sin) {
    const int Q = FNB / NTH;
    const int tid = threadIdx.x, lane = tid & 63, wid = tid >> 6;
    float Ls[FNB / NTH], Hs[FNB / NTH];
    float L = -INFINITY, H = INFINITY;
#pragma unroll
    for (int j = 0; j < Q; ++j) {
        Ls[j] = bsum[2 * (tid * Q + j)];
        Hs[j] = bsum[2 * (tid * Q + j) + 1];
        float Ln, Hn; combine(L, H, Ls[j], Hs[j], Ln, Hn); L = Ln; H = Hn;
    }
#pragma unroll
    for (int d = 1; d < 64; d <<= 1) {
        float Lp = __shfl_up(L, d), Hp = __shfl_up(H, d);
        if (lane >= d) { float Ln, Hn; combine(Lp, Hp, L, H, Ln, Hn); L = Ln; H = Hn; }
    }
    float eL = __shfl_up(L, 1), eH = __shfl_up(H, 1);
    if (lane == 0) { eL = -INFINITY; eH = INFINITY; }
    __shared__ float wL[NTH / 64], wH[NTH / 64];
    if (lane == 63) { wL[wid] = L; wH[wid] = H; }
    __syncthreads();
    float s = s0ptr[0];
    for (int w = 0; w < wid; ++w) s = fminf(fmaxf(s, wL[w]), wH[w]);
    s = fminf(fmaxf(s, eL), eH);
#pragma unroll
    for (int j = 0; j < Q; ++j) {
        sin[tid * Q + j] = s;
        s = fminf(fmaxf(s, Ls[j]), Hs[j]);
    }
}

__global__ __launch_bounds__(NTH) void pass3(const float* __restrict__ x,
                                             const float* __restrict__ kptr,
                                             const float* __restrict__ sin,
                                             float* __restrict__ out) {
    const float k  = kptr[0];
    const int tid  = threadIdx.x;
    const int bid  = blockIdx.x;
    const int lane = tid & 63;
    const int wid  = tid >> 6;
    const long base = ((long)bid * NTH + tid) * FSEG;
    const float4* xv = (const float4*)(x + base);

    float4 vsf[FSEG / 4];
#pragma unroll
    for (int i = 0; i < FSEG / 4; ++i) vsf[i] = xv[i];

    float L = -INFINITY, H = INFINITY;
#pragma unroll
    for (int i = 0; i < FSEG / 4; ++i) {
        float y;
        y = k * vsf[i].x; L = fminf(fmaxf(L, y), y + WPLAY); H = fminf(fmaxf(H, y), y + WPLAY);
        y = k * vsf[i].y; L = fminf(fmaxf(L, y), y + WPLAY); H = fminf(fmaxf(H, y), y + WPLAY);
        y = k * vsf[i].z; L = fminf(fmaxf(L, y), y + WPLAY); H = fminf(fmaxf(H, y), y + WPLAY);
        y = k * vsf[i].w; L = fminf(fmaxf(L, y), y + WPLAY); H = fminf(fmaxf(H, y), y + WPLAY);
    }
#pragma unroll
    for (int d = 1; d < 64; d <<= 1) {
        float Lp = __shfl_up(L, d), Hp = __shfl_up(H, d);
        if (lane >= d) { float Ln, Hn; combine(Lp, Hp, L, H, Ln, Hn); L = Ln; H = Hn; }
    }
    float eL = __shfl_up(L, 1), eH = __shfl_up(H, 1);
    if (lane == 0) { eL = -INFINITY; eH = INFINITY; }
    __shared__ float wLs[NTH / 64], wHs[NTH / 64];
    if (lane == 63) { wLs[wid] = L; wHs[wid] = H; }
    __syncthreads();
    float s = sin[bid];
    for (int w = 0; w < wid; ++w) s = fminf(fmaxf(s, wLs[w]), wHs[w]);
    s = fminf(fmaxf(s, eL), eH);

    float4* ov = (float4*)(out + base);
#pragma unroll
    for (int i = 0; i < FSEG / 4; ++i) {
        float4 o; float y;
        y = k * vsf[i].x; s = fminf(fmaxf(s, y), y + WPLAY); o.x = s;
        y = k * vsf[i].y; s = fminf(fmaxf(s, y), y + WPLAY); o.y = s;
        y = k * vsf[i].z; s = fminf(fmaxf(s, y), y + WPLAY); o.z = s;
        y = k * vsf[i].w; s = fminf(fmaxf(s, y), y + WPLAY); o.w = s;
        ov[i] = o;
    }
}

extern "C" void kernel_launch(void* const* d_in, const int* in_sizes, int n_in,
                              void* d_out, int out_size, void* d_ws, size_t ws_size,
                              hipStream_t stream) {
    const float* x  = (const float*)d_in[0];
    const float* st = (const float*)d_in[1];
    const float* kn = (const float*)d_in[2];
    float* out = (float*)d_out;

    unsigned long long* bsum = (unsigned long long*)d_ws;  // NB packed (L,H)

    void* args[] = {(void*)&x, (void*)&kn, (void*)&st, (void*)&bsum, (void*)&out};
    hipError_t err = hipLaunchCooperativeKernel((void*)fused, dim3(NB), dim3(NTH),
                                                args, 0, stream);
    if (err != hipSuccess) {
        // deterministic fallback: proven 3-pass path
        float* fb   = (float*)d_ws;
        float* fsin = fb + 2 * FNB;
        pass1<<<FNB, NTH, 0, stream>>>(x, kn, fb);
        pass2<<<1, NTH, 0, stream>>>(fb, st, fsin);
        pass3<<<FNB, NTH, 0, stream>>>(x, kn, fsin, out);
    }
}

// Round 3
// 113.238 us; speedup vs baseline: 2.0733x; 2.0733x over previous
//
#include <hip/hip_runtime.h>

// PlayCell hysteresis scan, single-pass decoupled lookback.
//   y[t]   = kernel * x[t]
//   out[t] = min(max(out[t-1], y[t]), y[t] + W)   (play operator, W = 1.0)
// Clamp maps are closed under composition -> associative scan over (L,H).
// combine(a then b): L = min(max(La,Lb),Hb), H = min(max(Ha,Lb),Hb).
// Collapse property: if a block aggregate has L==H, its inclusive prefix
// equals its aggregate (entry state irrelevant) -> publish INCLUSIVE before
// lookback; successors' lookback depth becomes 1. For N(0,|k|) data with
// W=1 over 8192 elems, collapse is essentially certain; correctness never
// depends on it (general aggregate path retained).

#define T_LEN   16777216
#define NTH     256
#define SEG     32
#define NB      (T_LEN / (NTH * SEG))   // 2048 blocks; NB*NTH*SEG == T_LEN
#define WPLAY   1.0f

#define FLAG_INVALID 0u
#define FLAG_AGG     1u
#define FLAG_INC     2u

__device__ __forceinline__ void combine(float La, float Ha, float Lb, float Hb,
                                        float& Lo, float& Ho) {
    Lo = fminf(fmaxf(La, Lb), Hb);
    Ho = fminf(fmaxf(Ha, Lb), Hb);
}

__device__ __forceinline__ unsigned long long packLH(float L, float H) {
    return ((unsigned long long)__float_as_uint(H) << 32) | (unsigned long long)__float_as_uint(L);
}
__device__ __forceinline__ void unpackLH(unsigned long long u, float& L, float& H) {
    L = __uint_as_float((unsigned)(u & 0xffffffffull));
    H = __uint_as_float((unsigned)(u >> 32));
}

__global__ __launch_bounds__(NTH, 4) void playscan(const float* __restrict__ x,
                                                   const float* __restrict__ kptr,
                                                   const float* __restrict__ s0ptr,
                                                   unsigned long long* __restrict__ pay,
                                                   unsigned* __restrict__ flags,
                                                   float* __restrict__ out) {
    const float k  = kptr[0];
    const int tid  = threadIdx.x;
    const int bid  = blockIdx.x;
    const int lane = tid & 63;
    const int wid  = tid >> 6;
    const long base = ((long)bid * NTH + tid) * SEG;
    const float4* xv = (const float4*)(x + base);

    // ---- load this thread's 32 elements (x read ONCE) ----
    float4 vs[SEG / 4];
#pragma unroll
    for (int i = 0; i < SEG / 4; ++i) vs[i] = xv[i];

    // ---- thread clamp summary ----
    float L = -INFINITY, H = INFINITY;
#pragma unroll
    for (int i = 0; i < SEG / 4; ++i) {
        float y;
        y = k * vs[i].x; L = fminf(fmaxf(L, y), y + WPLAY); H = fminf(fmaxf(H, y), y + WPLAY);
        y = k * vs[i].y; L = fminf(fmaxf(L, y), y + WPLAY); H = fminf(fmaxf(H, y), y + WPLAY);
        y = k * vs[i].z; L = fminf(fmaxf(L, y), y + WPLAY); H = fminf(fmaxf(H, y), y + WPLAY);
        y = k * vs[i].w; L = fminf(fmaxf(L, y), y + WPLAY); H = fminf(fmaxf(H, y), y + WPLAY);
    }

    // ---- ordered wave inclusive scan ----
#pragma unroll
    for (int d = 1; d < 64; d <<= 1) {
        float Lp = __shfl_up(L, d);
        float Hp = __shfl_up(H, d);
        if (lane >= d) { float Ln, Hn; combine(Lp, Hp, L, H, Ln, Hn); L = Ln; H = Hn; }
    }
    float eL = __shfl_up(L, 1), eH = __shfl_up(H, 1);
    if (lane == 0) { eL = -INFINITY; eH = INFINITY; }

    __shared__ float wL[NTH / 64], wH[NTH / 64];
    if (lane == 63) { wL[wid] = L; wH[wid] = H; }
    __syncthreads();

    // thread-exclusive prefix within block (pair form)
    float peL = -INFINITY, peH = INFINITY;
    for (int w = 0; w < wid; ++w) {
        float Ln, Hn; combine(peL, peH, wL[w], wH[w], Ln, Hn); peL = Ln; peH = Hn;
    }
    { float Ln, Hn; combine(peL, peH, eL, eH, Ln, Hn); peL = Ln; peH = Hn; }

    // ---- decoupled lookback (thread 0 only) ----
    __shared__ float sPL, sPH;
    if (tid == 0) {
        float aggL = wL[0], aggH = wH[0];
#pragma unroll
        for (int w = 1; w < NTH / 64; ++w) {
            float Ln, Hn; combine(aggL, aggH, wL[w], wH[w], Ln, Hn); aggL = Ln; aggH = Hn;
        }

        float PL = -INFINITY, PH = INFINITY;
        if (bid == 0) {
            // prefix = identity; inclusive = aggregate
            __hip_atomic_store(&pay[0], packLH(aggL, aggH),
                               __ATOMIC_RELAXED, __HIP_MEMORY_SCOPE_AGENT);
            __hip_atomic_store(&flags[0], FLAG_INC,
                               __ATOMIC_RELEASE, __HIP_MEMORY_SCOPE_AGENT);
        } else if (aggL == aggH) {
            // collapsed: inclusive == aggregate regardless of prefix.
            // Publish INC immediately (unblocks successors), then lookback.
            __hip_atomic_store(&pay[bid], packLH(aggL, aggH),
                               __ATOMIC_RELAXED, __HIP_MEMORY_SCOPE_AGENT);
            __hip_atomic_store(&flags[bid], FLAG_INC,
                               __ATOMIC_RELEASE, __HIP_MEMORY_SCOPE_AGENT);
            // lookback for our own entering prefix
            float accL = -INFINITY, accH = INFINITY;
            int j = bid - 1;
            while (true) {
                if (j < 0) { PL = accL; PH = accH; break; }
                unsigned f;
                do {
                    f = __hip_atomic_load(&flags[j], __ATOMIC_ACQUIRE, __HIP_MEMORY_SCOPE_AGENT);
                } while (f == FLAG_INVALID);
                unsigned long long u = __hip_atomic_load(&pay[j], __ATOMIC_RELAXED,
                                                         __HIP_MEMORY_SCOPE_AGENT);
                float vL, vH; unpackLH(u, vL, vH);
                float Ln, Hn; combine(vL, vH, accL, accH, Ln, Hn);
                if (f == FLAG_INC) { PL = Ln; PH = Hn; break; }
                accL = Ln; accH = Hn; --j;
            }
        } else {
            // general path: publish aggregate, lookback, then publish inclusive
            __hip_atomic_store(&pay[bid], packLH(aggL, aggH),
                               __ATOMIC_RELAXED, __HIP_MEMORY_SCOPE_AGENT);
            __hip_atomic_store(&flags[bid], FLAG_AGG,
                               __ATOMIC_RELEASE, __HIP_MEMORY_SCOPE_AGENT);
            float accL = -INFINITY, accH = INFINITY;
            int j = bid - 1;
            while (true) {
                if (j < 0) { PL = accL; PH = accH; break; }
                unsigned f;
                do {
                    f = __hip_atomic_load(&flags[j], __ATOMIC_ACQUIRE, __HIP_MEMORY_SCOPE_AGENT);
                } while (f == FLAG_INVALID);
                unsigned long long u = __hip_atomic_load(&pay[j], __ATOMIC_RELAXED,
                                                         __HIP_MEMORY_SCOPE_AGENT);
                float vL, vH; unpackLH(u, vL, vH);
                float Ln, Hn; combine(vL, vH, accL, accH, Ln, Hn);
                if (f == FLAG_INC) { PL = Ln; PH = Hn; break; }
                accL = Ln; accH = Hn; --j;
            }
            float iL, iH; combine(PL, PH, aggL, aggH, iL, iH);
            __hip_atomic_store(&pay[bid], packLH(iL, iH),
                               __ATOMIC_RELAXED, __HIP_MEMORY_SCOPE_AGENT);
            __hip_atomic_store(&flags[bid], FLAG_INC,
                               __ATOMIC_RELEASE, __HIP_MEMORY_SCOPE_AGENT);
        }
        sPL = PL; sPH = PH;
    }
    __syncthreads();

    // ---- entering state + serial emit from registers ----
    float s = fminf(fmaxf(s0ptr[0], sPL), sPH);  // block entering state
    s = fminf(fmaxf(s, peL), peH);               // + in-block thread prefix

    float4* ov = (float4*)(out + base);
#pragma unroll
    for (int i = 0; i < SEG / 4; ++i) {
        float4 o; float y;
        y = k * vs[i].x; s = fminf(fmaxf(s, y), y + WPLAY); o.x = s;
        y = k * vs[i].y; s = fminf(fmaxf(s, y), y + WPLAY); o.y = s;
        y = k * vs[i].z; s = fminf(fmaxf(s, y), y + WPLAY); o.z = s;
        y = k * vs[i].w; s = fminf(fmaxf(s, y), y + WPLAY); o.w = s;
        ov[i] = o;
    }
}

extern "C" void kernel_launch(void* const* d_in, const int* in_sizes, int n_in,
                              void* d_out, int out_size, void* d_ws, size_t ws_size,
                              hipStream_t stream) {
    const float* x  = (const float*)d_in[0];   // (T,) float32
    const float* st = (const float*)d_in[1];   // scalar initial state
    const float* kn = (const float*)d_in[2];   // scalar kernel weight
    float* out = (float*)d_out;

    // workspace layout: pay[NB] (8B each) | flags[NB] (4B each)
    unsigned long long* pay = (unsigned long long*)d_ws;
    unsigned* flags = (unsigned*)((char*)d_ws + NB * sizeof(unsigned long long));

    // reset flags every call (ws is NOT re-poisoned between replays)
    hipMemsetAsync(flags, 0, NB * sizeof(unsigned), stream);

    playscan<<<NB, NTH, 0, stream>>>(x, kn, st, pay, flags, out);
}

// Round 4
// 89.414 us; speedup vs baseline: 2.6257x; 1.2664x over previous
//
#include <hip/hip_runtime.h>

// PlayCell hysteresis scan, single-pass decoupled lookback, RELAXED-only.
//   y[t]   = kernel * x[t]
//   out[t] = min(max(out[t-1], y[t]), y[t] + W)   (play operator, W = 1.0)
// Clamp maps compose associatively over (L,H):
//   combine(a then b): L = min(max(La,Lb),Hb), H = min(max(Ha,Lb),Hb).
// Collapse: if a block aggregate has L==H, its inclusive prefix equals its
// aggregate -> publish INCLUSIVE before lookback; successors stop at depth 1.
//
// Synchronization design: NO acquire/release (agent-scope acquire emits a
// per-XCD L2 invalidate on gfx950 -- round-3 showed this poisons all in-flight
// traffic). Payloads are single 8-byte words; L,H are provably finite, so the
// all-ones NaN pattern is an unreachable sentinel. A relaxed 8B atomic load
// either sees the sentinel or the complete published value.

#define T_LEN   16777216
#define NTH     256
#define SEG     32
#define NB      (T_LEN / (NTH * SEG))   // 2048 blocks; NB*NTH*SEG == T_LEN
#define WPLAY   1.0f

#define SENT    0xFFFFFFFFFFFFFFFFull

__device__ __forceinline__ void combine(float La, float Ha, float Lb, float Hb,
                                        float& Lo, float& Ho) {
    Lo = fminf(fmaxf(La, Lb), Hb);
    Ho = fminf(fmaxf(Ha, Lb), Hb);
}

__device__ __forceinline__ unsigned long long packLH(float L, float H) {
    return ((unsigned long long)__float_as_uint(H) << 32) | (unsigned long long)__float_as_uint(L);
}
__device__ __forceinline__ void unpackLH(unsigned long long u, float& L, float& H) {
    L = __uint_as_float((unsigned)(u & 0xffffffffull));
    H = __uint_as_float((unsigned)(u >> 32));
}

__global__ __launch_bounds__(NTH, 8) void playscan(const float* __restrict__ x,
                                                   const float* __restrict__ kptr,
                                                   const float* __restrict__ s0ptr,
                                                   unsigned long long* __restrict__ payAgg,
                                                   unsigned long long* __restrict__ payInc,
                                                   float* __restrict__ out) {
    const float k  = kptr[0];
    const int tid  = threadIdx.x;
    const int bid  = blockIdx.x;
    const int lane = tid & 63;
    const int wid  = tid >> 6;
    const long base = ((long)bid * NTH + tid) * SEG;
    const float4* xv = (const float4*)(x + base);

    // ---- load this thread's 32 elements (x read ONCE) ----
    float4 vs[SEG / 4];
#pragma unroll
    for (int i = 0; i < SEG / 4; ++i) vs[i] = xv[i];

    // ---- thread clamp summary ----
    float L = -INFINITY, H = INFINITY;
#pragma unroll
    for (int i = 0; i < SEG / 4; ++i) {
        float y;
        y = k * vs[i].x; L = fminf(fmaxf(L, y), y + WPLAY); H = fminf(fmaxf(H, y), y + WPLAY);
        y = k * vs[i].y; L = fminf(fmaxf(L, y), y + WPLAY); H = fminf(fmaxf(H, y), y + WPLAY);
        y = k * vs[i].z; L = fminf(fmaxf(L, y), y + WPLAY); H = fminf(fmaxf(H, y), y + WPLAY);
        y = k * vs[i].w; L = fminf(fmaxf(L, y), y + WPLAY); H = fminf(fmaxf(H, y), y + WPLAY);
    }

    // ---- ordered wave inclusive scan ----
#pragma unroll
    for (int d = 1; d < 64; d <<= 1) {
        float Lp = __shfl_up(L, d);
        float Hp = __shfl_up(H, d);
        if (lane >= d) { float Ln, Hn; combine(Lp, Hp, L, H, Ln, Hn); L = Ln; H = Hn; }
    }
    float eL = __shfl_up(L, 1), eH = __shfl_up(H, 1);
    if (lane == 0) { eL = -INFINITY; eH = INFINITY; }

    __shared__ float wL[NTH / 64], wH[NTH / 64];
    if (lane == 63) { wL[wid] = L; wH[wid] = H; }
    __syncthreads();

    // thread-exclusive prefix within block (pair form)
    float peL = -INFINITY, peH = INFINITY;
    for (int w = 0; w < wid; ++w) {
        float Ln, Hn; combine(peL, peH, wL[w], wH[w], Ln, Hn); peL = Ln; peH = Hn;
    }
    { float Ln, Hn; combine(peL, peH, eL, eH, Ln, Hn); peL = Ln; peH = Hn; }

    // ---- decoupled lookback (thread 0 only), relaxed atomics only ----
    __shared__ float sPL, sPH;
    if (tid == 0) {
        float aggL = wL[0], aggH = wH[0];
#pragma unroll
        for (int w = 1; w < NTH / 64; ++w) {
            float Ln, Hn; combine(aggL, aggH, wL[w], wH[w], Ln, Hn); aggL = Ln; aggH = Hn;
        }

        float PL = -INFINITY, PH = INFINITY;
        if (bid == 0) {
            __hip_atomic_store(&payInc[0], packLH(aggL, aggH),
                               __ATOMIC_RELAXED, __HIP_MEMORY_SCOPE_AGENT);
        } else if (aggL == aggH) {
            // collapsed: inclusive == aggregate regardless of prefix.
            __hip_atomic_store(&payInc[bid], packLH(aggL, aggH),
                               __ATOMIC_RELAXED, __HIP_MEMORY_SCOPE_AGENT);
            float accL = -INFINITY, accH = INFINITY;
            int j = bid - 1;
            while (true) {
                unsigned long long ui = __hip_atomic_load(&payInc[j], __ATOMIC_RELAXED,
                                                          __HIP_MEMORY_SCOPE_AGENT);
                if (ui != SENT) {
                    float vL, vH; unpackLH(ui, vL, vH);
                    combine(vL, vH, accL, accH, PL, PH);
                    break;
                }
                unsigned long long ua = __hip_atomic_load(&payAgg[j], __ATOMIC_RELAXED,
                                                          __HIP_MEMORY_SCOPE_AGENT);
                if (ua != SENT) {
                    float vL, vH; unpackLH(ua, vL, vH);
                    float Ln, Hn; combine(vL, vH, accL, accH, Ln, Hn);
                    accL = Ln; accH = Hn;
                    if (--j < 0) { PL = accL; PH = accH; break; }
                }
            }
        } else {
            // general path: publish aggregate, lookback, publish inclusive
            __hip_atomic_store(&payAgg[bid], packLH(aggL, aggH),
                               __ATOMIC_RELAXED, __HIP_MEMORY_SCOPE_AGENT);
            float accL = -INFINITY, accH = INFINITY;
            int j = bid - 1;
            while (true) {
                unsigned long long ui = __hip_atomic_load(&payInc[j], __ATOMIC_RELAXED,
                                                          __HIP_MEMORY_SCOPE_AGENT);
                if (ui != SENT) {
                    float vL, vH; unpackLH(ui, vL, vH);
                    combine(vL, vH, accL, accH, PL, PH);
                    break;
                }
                unsigned long long ua = __hip_atomic_load(&payAgg[j], __ATOMIC_RELAXED,
                                                          __HIP_MEMORY_SCOPE_AGENT);
                if (ua != SENT) {
                    float vL, vH; unpackLH(ua, vL, vH);
                    float Ln, Hn; combine(vL, vH, accL, accH, Ln, Hn);
                    accL = Ln; accH = Hn;
                    if (--j < 0) { PL = accL; PH = accH; break; }
                }
            }
            float iL, iH; combine(PL, PH, aggL, aggH, iL, iH);
            __hip_atomic_store(&payInc[bid], packLH(iL, iH),
                               __ATOMIC_RELAXED, __HIP_MEMORY_SCOPE_AGENT);
        }
        sPL = PL; sPH = PH;
    }
    __syncthreads();

    // ---- entering state + serial emit from registers ----
    float s = fminf(fmaxf(s0ptr[0], sPL), sPH);  // block entering state
    s = fminf(fmaxf(s, peL), peH);               // + in-block thread prefix

    float4* ov = (float4*)(out + base);
#pragma unroll
    for (int i = 0; i < SEG / 4; ++i) {
        float4 o; float y;
        y = k * vs[i].x; s = fminf(fmaxf(s, y), y + WPLAY); o.x = s;
        y = k * vs[i].y; s = fminf(fmaxf(s, y), y + WPLAY); o.y = s;
        y = k * vs[i].z; s = fminf(fmaxf(s, y), y + WPLAY); o.z = s;
        y = k * vs[i].w; s = fminf(fmaxf(s, y), y + WPLAY); o.w = s;
        ov[i] = o;
    }
}

extern "C" void kernel_launch(void* const* d_in, const int* in_sizes, int n_in,
                              void* d_out, int out_size, void* d_ws, size_t ws_size,
                              hipStream_t stream) {
    const float* x  = (const float*)d_in[0];   // (T,) float32
    const float* st = (const float*)d_in[1];   // scalar initial state
    const float* kn = (const float*)d_in[2];   // scalar kernel weight
    float* out = (float*)d_out;

    // workspace: payAgg[NB] | payInc[NB], both 8B words, sentinel = all-ones
    unsigned long long* payAgg = (unsigned long long*)d_ws;
    unsigned long long* payInc = payAgg + NB;

    // re-arm sentinels every call (ws is not re-poisoned between replays)
    hipMemsetAsync(payAgg, 0xFF, 2 * NB * sizeof(unsigned long long), stream);

    playscan<<<NB, NTH, 0, stream>>>(x, kn, st, payAgg, payInc, out);
}

// Round 5
// 42.301 us; speedup vs baseline: 5.5502x; 2.1138x over previous
//
#include <hip/hip_runtime.h>

// PlayCell hysteresis scan, single-pass decoupled lookback, RELAXED-only.
//   y[t]   = kernel * x[t]
//   out[t] = min(max(out[t-1], y[t]), y[t] + W)   (play operator, W = 1.0)
// Clamp maps compose associatively over (L,H):
//   combine(a then b): L = min(max(La,Lb),Hb), H = min(max(Ha,Lb),Hb).
// Collapse: if a block aggregate has L==H, its inclusive prefix equals its
// aggregate -> publish INCLUSIVE before lookback; successors stop at depth 1.
//
// Sync design: NO acquire/release (agent-scope acquire emits per-XCD L2
// invalidates on gfx950 -- round 3 measured 5x slowdown). Payloads are single
// 8-byte words; L,H are provably finite after >=1 element, so all-ones is an
// unreachable sentinel. Relaxed 8B atomic load sees sentinel or full value.
//
// Occupancy: __launch_bounds__(256, 4) -> VGPR cap 128. Round 3 measured 44
// VGPRs, no scratch. Round 4's (256,8) capped VGPRs at 32 and spilled the
// 32-float chunk (WRITE_SIZE 228 MB vs 64 ideal) -- do NOT tighten this.

#define T_LEN   16777216
#define NTH     256
#define SEG     32
#define NB      (T_LEN / (NTH * SEG))   // 2048 blocks; NB*NTH*SEG == T_LEN
#define WPLAY   1.0f

#define SENT    0xFFFFFFFFFFFFFFFFull

__device__ __forceinline__ void combine(float La, float Ha, float Lb, float Hb,
                                        float& Lo, float& Ho) {
    Lo = fminf(fmaxf(La, Lb), Hb);
    Ho = fminf(fmaxf(Ha, Lb), Hb);
}

__device__ __forceinline__ unsigned long long packLH(float L, float H) {
    return ((unsigned long long)__float_as_uint(H) << 32) | (unsigned long long)__float_as_uint(L);
}
__device__ __forceinline__ void unpackLH(unsigned long long u, float& L, float& H) {
    L = __uint_as_float((unsigned)(u & 0xffffffffull));
    H = __uint_as_float((unsigned)(u >> 32));
}

__global__ __launch_bounds__(NTH, 4) void playscan(const float* __restrict__ x,
                                                   const float* __restrict__ kptr,
                                                   const float* __restrict__ s0ptr,
                                                   unsigned long long* __restrict__ payAgg,
                                                   unsigned long long* __restrict__ payInc,
                                                   float* __restrict__ out) {
    const float k  = kptr[0];
    const int tid  = threadIdx.x;
    const int bid  = blockIdx.x;
    const int lane = tid & 63;
    const int wid  = tid >> 6;
    const long base = ((long)bid * NTH + tid) * SEG;
    const float4* xv = (const float4*)(x + base);

    // ---- load this thread's 32 elements (x read ONCE) ----
    float4 vs[SEG / 4];
#pragma unroll
    for (int i = 0; i < SEG / 4; ++i) vs[i] = xv[i];

    // ---- thread clamp summary ----
    float L = -INFINITY, H = INFINITY;
#pragma unroll
    for (int i = 0; i < SEG / 4; ++i) {
        float y;
        y = k * vs[i].x; L = fminf(fmaxf(L, y), y + WPLAY); H = fminf(fmaxf(H, y), y + WPLAY);
        y = k * vs[i].y; L = fminf(fmaxf(L, y), y + WPLAY); H = fminf(fmaxf(H, y), y + WPLAY);
        y = k * vs[i].z; L = fminf(fmaxf(L, y), y + WPLAY); H = fminf(fmaxf(H, y), y + WPLAY);
        y = k * vs[i].w; L = fminf(fmaxf(L, y), y + WPLAY); H = fminf(fmaxf(H, y), y + WPLAY);
    }

    // ---- ordered wave inclusive scan ----
#pragma unroll
    for (int d = 1; d < 64; d <<= 1) {
        float Lp = __shfl_up(L, d);
        float Hp = __shfl_up(H, d);
        if (lane >= d) { float Ln, Hn; combine(Lp, Hp, L, H, Ln, Hn); L = Ln; H = Hn; }
    }
    float eL = __shfl_up(L, 1), eH = __shfl_up(H, 1);
    if (lane == 0) { eL = -INFINITY; eH = INFINITY; }

    __shared__ float wL[NTH / 64], wH[NTH / 64];
    if (lane == 63) { wL[wid] = L; wH[wid] = H; }
    __syncthreads();

    // thread-exclusive prefix within block (pair form)
    float peL = -INFINITY, peH = INFINITY;
    for (int w = 0; w < wid; ++w) {
        float Ln, Hn; combine(peL, peH, wL[w], wH[w], Ln, Hn); peL = Ln; peH = Hn;
    }
    { float Ln, Hn; combine(peL, peH, eL, eH, Ln, Hn); peL = Ln; peH = Hn; }

    // ---- decoupled lookback (thread 0 only), relaxed atomics only ----
    __shared__ float sPL, sPH;
    if (tid == 0) {
        float aggL = wL[0], aggH = wH[0];
#pragma unroll
        for (int w = 1; w < NTH / 64; ++w) {
            float Ln, Hn; combine(aggL, aggH, wL[w], wH[w], Ln, Hn); aggL = Ln; aggH = Hn;
        }

        float PL = -INFINITY, PH = INFINITY;
        if (bid == 0) {
            __hip_atomic_store(&payInc[0], packLH(aggL, aggH),
                               __ATOMIC_RELAXED, __HIP_MEMORY_SCOPE_AGENT);
        } else if (aggL == aggH) {
            // collapsed: inclusive == aggregate regardless of prefix.
            __hip_atomic_store(&payInc[bid], packLH(aggL, aggH),
                               __ATOMIC_RELAXED, __HIP_MEMORY_SCOPE_AGENT);
            float accL = -INFINITY, accH = INFINITY;
            int j = bid - 1;
            while (true) {
                unsigned long long ui = __hip_atomic_load(&payInc[j], __ATOMIC_RELAXED,
                                                          __HIP_MEMORY_SCOPE_AGENT);
                if (ui != SENT) {
                    float vL, vH; unpackLH(ui, vL, vH);
                    combine(vL, vH, accL, accH, PL, PH);
                    break;
                }
                unsigned long long ua = __hip_atomic_load(&payAgg[j], __ATOMIC_RELAXED,
                                                          __HIP_MEMORY_SCOPE_AGENT);
                if (ua != SENT) {
                    float vL, vH; unpackLH(ua, vL, vH);
                    float Ln, Hn; combine(vL, vH, accL, accH, Ln, Hn);
                    accL = Ln; accH = Hn;
                    if (--j < 0) { PL = accL; PH = accH; break; }
                }
            }
        } else {
            // general path: publish aggregate, lookback, publish inclusive
            __hip_atomic_store(&payAgg[bid], packLH(aggL, aggH),
                               __ATOMIC_RELAXED, __HIP_MEMORY_SCOPE_AGENT);
            float accL = -INFINITY, accH = INFINITY;
            int j = bid - 1;
            while (true) {
                unsigned long long ui = __hip_atomic_load(&payInc[j], __ATOMIC_RELAXED,
                                                          __HIP_MEMORY_SCOPE_AGENT);
                if (ui != SENT) {
                    float vL, vH; unpackLH(ui, vL, vH);
                    combine(vL, vH, accL, accH, PL, PH);
                    break;
                }
                unsigned long long ua = __hip_atomic_load(&payAgg[j], __ATOMIC_RELAXED,
                                                          __HIP_MEMORY_SCOPE_AGENT);
                if (ua != SENT) {
                    float vL, vH; unpackLH(ua, vL, vH);
                    float Ln, Hn; combine(vL, vH, accL, accH, Ln, Hn);
                    accL = Ln; accH = Hn;
                    if (--j < 0) { PL = accL; PH = accH; break; }
                }
            }
            float iL, iH; combine(PL, PH, aggL, aggH, iL, iH);
            __hip_atomic_store(&payInc[bid], packLH(iL, iH),
                               __ATOMIC_RELAXED, __HIP_MEMORY_SCOPE_AGENT);
        }
        sPL = PL; sPH = PH;
    }
    __syncthreads();

    // ---- entering state + serial emit from registers ----
    float s = fminf(fmaxf(s0ptr[0], sPL), sPH);  // block entering state
    s = fminf(fmaxf(s, peL), peH);               // + in-block thread prefix

    float4* ov = (float4*)(out + base);
#pragma unroll
    for (int i = 0; i < SEG / 4; ++i) {
        float4 o; float y;
        y = k * vs[i].x; s = fminf(fmaxf(s, y), y + WPLAY); o.x = s;
        y = k * vs[i].y; s = fminf(fmaxf(s, y), y + WPLAY); o.y = s;
        y = k * vs[i].z; s = fminf(fmaxf(s, y), y + WPLAY); o.z = s;
        y = k * vs[i].w; s = fminf(fmaxf(s, y), y + WPLAY); o.w = s;
        ov[i] = o;
    }
}

extern "C" void kernel_launch(void* const* d_in, const int* in_sizes, int n_in,
                              void* d_out, int out_size, void* d_ws, size_t ws_size,
                              hipStream_t stream) {
    const float* x  = (const float*)d_in[0];   // (T,) float32
    const float* st = (const float*)d_in[1];   // scalar initial state
    const float* kn = (const float*)d_in[2];   // scalar kernel weight
    float* out = (float*)d_out;

    // workspace: payAgg[NB] | payInc[NB], both 8B words, sentinel = all-ones
    unsigned long long* payAgg = (unsigned long long*)d_ws;
    unsigned long long* payInc = payAgg + NB;

    // re-arm sentinels every call (ws is not re-poisoned between replays)
    hipMemsetAsync(payAgg, 0xFF, 2 * NB * sizeof(unsigned long long), stream);

    playscan<<<NB, NTH, 0, stream>>>(x, kn, st, payAgg, payInc, out);
}

// Round 6
// 41.474 us; speedup vs baseline: 5.6609x; 1.0199x over previous
//
#include <hip/hip_runtime.h>

// PlayCell hysteresis scan, single-pass decoupled lookback, RELAXED-only.
//   y[t]   = kernel * x[t]
//   out[t] = min(max(out[t-1], y[t]), y[t] + W)   (play operator, W = 1.0)
// Clamp maps compose associatively over (L,H):
//   combine(a then b): L = min(max(La,Lb),Hb), H = min(max(Ha,Lb),Hb).
// Collapse: if a block aggregate has L==H, its inclusive prefix equals its
// aggregate -> publish INCLUSIVE before lookback; successors stop at depth 1.
//
// Sync design: NO acquire/release (agent-scope acquire emits per-XCD L2
// invalidates on gfx950 -- round 3 measured 5x slowdown). Payloads are single
// 8-byte words; L,H are provably finite after >=1 element, so all-ones is an
// unreachable sentinel. Relaxed 8B atomic load sees sentinel or full value.
//
// Occupancy history:
//   r3: SEG=32, (256,4): VGPR=44, no spill, 113 us (acquire/release poison)
//   r4: SEG=32, (256,8): VGPR capped 32 -> SPILL (WRITE 228 MB), 89 us
//   r5: SEG=32, (256,4): VGPR=44, no spill, 40 us kernel, 2.5 TB/s,
//       Occupancy 34.5% -> phase-locked, latency-bound.
//   r6 (this): SEG=16, (256,8): ~36-44 VGPR fits the 64 cap -> 8 blocks/CU,
//       staggered phases, full occupancy. Verify: WRITE_SIZE stays ~66 MB.

#define T_LEN   16777216
#define NTH     256
#define SEG     16
#define NB      (T_LEN / (NTH * SEG))   // 4096 blocks; NB*NTH*SEG == T_LEN
#define WPLAY   1.0f

#define SENT    0xFFFFFFFFFFFFFFFFull

__device__ __forceinline__ void combine(float La, float Ha, float Lb, float Hb,
                                        float& Lo, float& Ho) {
    Lo = fminf(fmaxf(La, Lb), Hb);
    Ho = fminf(fmaxf(Ha, Lb), Hb);
}

__device__ __forceinline__ unsigned long long packLH(float L, float H) {
    return ((unsigned long long)__float_as_uint(H) << 32) | (unsigned long long)__float_as_uint(L);
}
__device__ __forceinline__ void unpackLH(unsigned long long u, float& L, float& H) {
    L = __uint_as_float((unsigned)(u & 0xffffffffull));
    H = __uint_as_float((unsigned)(u >> 32));
}

__global__ __launch_bounds__(NTH, 8) void playscan(const float* __restrict__ x,
                                                   const float* __restrict__ kptr,
                                                   const float* __restrict__ s0ptr,
                                                   unsigned long long* __restrict__ payAgg,
                                                   unsigned long long* __restrict__ payInc,
                                                   float* __restrict__ out) {
    const float k  = kptr[0];
    const int tid  = threadIdx.x;
    const int bid  = blockIdx.x;
    const int lane = tid & 63;
    const int wid  = tid >> 6;
    const long base = ((long)bid * NTH + tid) * SEG;
    const float4* xv = (const float4*)(x + base);

    // ---- load this thread's 16 elements (x read ONCE) ----
    float4 vs[SEG / 4];
#pragma unroll
    for (int i = 0; i < SEG / 4; ++i) vs[i] = xv[i];

    // ---- thread clamp summary ----
    float L = -INFINITY, H = INFINITY;
#pragma unroll
    for (int i = 0; i < SEG / 4; ++i) {
        float y;
        y = k * vs[i].x; L = fminf(fmaxf(L, y), y + WPLAY); H = fminf(fmaxf(H, y), y + WPLAY);
        y = k * vs[i].y; L = fminf(fmaxf(L, y), y + WPLAY); H = fminf(fmaxf(H, y), y + WPLAY);
        y = k * vs[i].z; L = fminf(fmaxf(L, y), y + WPLAY); H = fminf(fmaxf(H, y), y + WPLAY);
        y = k * vs[i].w; L = fminf(fmaxf(L, y), y + WPLAY); H = fminf(fmaxf(H, y), y + WPLAY);
    }

    // ---- ordered wave inclusive scan ----
#pragma unroll
    for (int d = 1; d < 64; d <<= 1) {
        float Lp = __shfl_up(L, d);
        float Hp = __shfl_up(H, d);
        if (lane >= d) { float Ln, Hn; combine(Lp, Hp, L, H, Ln, Hn); L = Ln; H = Hn; }
    }
    float eL = __shfl_up(L, 1), eH = __shfl_up(H, 1);
    if (lane == 0) { eL = -INFINITY; eH = INFINITY; }

    __shared__ float wL[NTH / 64], wH[NTH / 64];
    if (lane == 63) { wL[wid] = L; wH[wid] = H; }
    __syncthreads();

    // thread-exclusive prefix within block (pair form)
    float peL = -INFINITY, peH = INFINITY;
    for (int w = 0; w < wid; ++w) {
        float Ln, Hn; combine(peL, peH, wL[w], wH[w], Ln, Hn); peL = Ln; peH = Hn;
    }
    { float Ln, Hn; combine(peL, peH, eL, eH, Ln, Hn); peL = Ln; peH = Hn; }

    // ---- decoupled lookback (thread 0 only), relaxed atomics only ----
    __shared__ float sPL, sPH;
    if (tid == 0) {
        float aggL = wL[0], aggH = wH[0];
#pragma unroll
        for (int w = 1; w < NTH / 64; ++w) {
            float Ln, Hn; combine(aggL, aggH, wL[w], wH[w], Ln, Hn); aggL = Ln; aggH = Hn;
        }

        float PL = -INFINITY, PH = INFINITY;
        if (bid == 0) {
            __hip_atomic_store(&payInc[0], packLH(aggL, aggH),
                               __ATOMIC_RELAXED, __HIP_MEMORY_SCOPE_AGENT);
        } else if (aggL == aggH) {
            // collapsed: inclusive == aggregate regardless of prefix.
            __hip_atomic_store(&payInc[bid], packLH(aggL, aggH),
                               __ATOMIC_RELAXED, __HIP_MEMORY_SCOPE_AGENT);
            float accL = -INFINITY, accH = INFINITY;
            int j = bid - 1;
            while (true) {
                unsigned long long ui = __hip_atomic_load(&payInc[j], __ATOMIC_RELAXED,
                                                          __HIP_MEMORY_SCOPE_AGENT);
                if (ui != SENT) {
                    float vL, vH; unpackLH(ui, vL, vH);
                    combine(vL, vH, accL, accH, PL, PH);
                    break;
                }
                unsigned long long ua = __hip_atomic_load(&payAgg[j], __ATOMIC_RELAXED,
                                                          __HIP_MEMORY_SCOPE_AGENT);
                if (ua != SENT) {
                    float vL, vH; unpackLH(ua, vL, vH);
                    float Ln, Hn; combine(vL, vH, accL, accH, Ln, Hn);
                    accL = Ln; accH = Hn;
                    if (--j < 0) { PL = accL; PH = accH; break; }
                }
            }
        } else {
            // general path: publish aggregate, lookback, publish inclusive
            __hip_atomic_store(&payAgg[bid], packLH(aggL, aggH),
                               __ATOMIC_RELAXED, __HIP_MEMORY_SCOPE_AGENT);
            float accL = -INFINITY, accH = INFINITY;
            int j = bid - 1;
            while (true) {
                unsigned long long ui = __hip_atomic_load(&payInc[j], __ATOMIC_RELAXED,
                                                          __HIP_MEMORY_SCOPE_AGENT);
                if (ui != SENT) {
                    float vL, vH; unpackLH(ui, vL, vH);
                    combine(vL, vH, accL, accH, PL, PH);
                    break;
                }
                unsigned long long ua = __hip_atomic_load(&payAgg[j], __ATOMIC_RELAXED,
                                                          __HIP_MEMORY_SCOPE_AGENT);
                if (ua != SENT) {
                    float vL, vH; unpackLH(ua, vL, vH);
                    float Ln, Hn; combine(vL, vH, accL, accH, Ln, Hn);
                    accL = Ln; accH = Hn;
                    if (--j < 0) { PL = accL; PH = accH; break; }
                }
            }
            float iL, iH; combine(PL, PH, aggL, aggH, iL, iH);
            __hip_atomic_store(&payInc[bid], packLH(iL, iH),
                               __ATOMIC_RELAXED, __HIP_MEMORY_SCOPE_AGENT);
        }
        sPL = PL; sPH = PH;
    }
    __syncthreads();

    // ---- entering state + serial emit from registers ----
    float s = fminf(fmaxf(s0ptr[0], sPL), sPH);  // block entering state
    s = fminf(fmaxf(s, peL), peH);               // + in-block thread prefix

    float4* ov = (float4*)(out + base);
#pragma unroll
    for (int i = 0; i < SEG / 4; ++i) {
        float4 o; float y;
        y = k * vs[i].x; s = fminf(fmaxf(s, y), y + WPLAY); o.x = s;
        y = k * vs[i].y; s = fminf(fmaxf(s, y), y + WPLAY); o.y = s;
        y = k * vs[i].z; s = fminf(fmaxf(s, y), y + WPLAY); o.z = s;
        y = k * vs[i].w; s = fminf(fmaxf(s, y), y + WPLAY); o.w = s;
        ov[i] = o;
    }
}

extern "C" void kernel_launch(void* const* d_in, const int* in_sizes, int n_in,
                              void* d_out, int out_size, void* d_ws, size_t ws_size,
                              hipStream_t stream) {
    const float* x  = (const float*)d_in[0];   // (T,) float32
    const float* st = (const float*)d_in[1];   // scalar initial state
    const float* kn = (const float*)d_in[2];   // scalar kernel weight
    float* out = (float*)d_out;

    // workspace: payAgg[NB] | payInc[NB], both 8B words, sentinel = all-ones
    unsigned long long* payAgg = (unsigned long long*)d_ws;
    unsigned long long* payInc = payAgg + NB;

    // re-arm sentinels every call (ws is not re-poisoned between replays)
    hipMemsetAsync(payAgg, 0xFF, 2 * NB * sizeof(unsigned long long), stream);

    playscan<<<NB, NTH, 0, stream>>>(x, kn, st, payAgg, payInc, out);
}